// Round 2
// baseline (674.400 us; speedup 1.0000x reference)
//
#include <hip/hip_runtime.h>

#define NEGF (-3.402823466e38f)

constexpr int H  = 8,  DH = 32, DN = 256, DE = 128;
constexpr int RR = 128, WW = 256;
constexpr int MROWS = RR * WW;     // 32768 token rows
constexpr int NQKVG = 1024;        // q(256)|k(256)|v(256)|g(256)

__device__ __forceinline__ float wred(float v) {
#pragma unroll
  for (int off = 32; off > 0; off >>= 1) v += __shfl_xor(v, off, 64);
  return v;
}

// ---------------- K1: LayerNorm(x) -> xn  [32768 x 256] ----------------
__global__ __launch_bounds__(256) void k_ln_x(const float* __restrict__ x,
                                              const float* __restrict__ g,
                                              const float* __restrict__ b,
                                              float* __restrict__ xn) {
  const int wave = threadIdx.x >> 6, lane = threadIdx.x & 63;
  const int row = (blockIdx.x << 2) + wave;
  const float4 v = ((const float4*)(x + (size_t)row * DN))[lane];
  float s  = v.x + v.y + v.z + v.w;
  float s2 = v.x*v.x + v.y*v.y + v.z*v.z + v.w*v.w;
  s = wred(s); s2 = wred(s2);
  const float mu = s * (1.f / DN);
  const float rs = rsqrtf(s2 * (1.f / DN) - mu * mu + 1e-5f);
  const float4 gg = ((const float4*)g)[lane];
  const float4 bb = ((const float4*)b)[lane];
  float4 o;
  o.x = (v.x - mu) * rs * gg.x + bb.x;
  o.y = (v.y - mu) * rs * gg.y + bb.y;
  o.z = (v.z - mu) * rs * gg.z + bb.z;
  o.w = (v.w - mu) * rs * gg.w + bb.w;
  ((float4*)(xn + (size_t)row * DN))[lane] = o;
}

// ------- K2: LayerNorm(edges) @ W_edge -> biasT[h][j][i], edge-masked -------
__global__ __launch_bounds__(256) void k_bias(const float* __restrict__ edges,
                                              const int* __restrict__ emask,
                                              const float* __restrict__ g,
                                              const float* __restrict__ b,
                                              const float* __restrict__ We,
                                              float* __restrict__ biasT) {
  const int wave = threadIdx.x >> 6, lane = threadIdx.x & 63;
  const int p = (blockIdx.x << 2) + wave;   // p = j*WW + i
  const int i = p & (WW - 1), j = p >> 8;
  const float2 e = ((const float2*)(edges + (size_t)(i * WW + j) * DE))[lane];
  float s = e.x + e.y, s2 = e.x*e.x + e.y*e.y;
  s = wred(s); s2 = wred(s2);
  const float mu = s * (1.f / DE);
  const float rs = rsqrtf(s2 * (1.f / DE) - mu * mu + 1e-5f);
  const float2 gg = ((const float2*)g)[lane];
  const float2 bb = ((const float2*)b)[lane];
  const float n0 = (e.x - mu) * rs * gg.x + bb.x;
  const float n1 = (e.y - mu) * rs * gg.y + bb.y;
  const float* w0 = We + (lane * 2) * H;
  float acc[H];
#pragma unroll
  for (int h = 0; h < H; ++h) acc[h] = n0 * w0[h] + n1 * w0[H + h];
#pragma unroll
  for (int off = 32; off > 0; off >>= 1)
#pragma unroll
    for (int h = 0; h < H; ++h) acc[h] += __shfl_xor(acc[h], off, 64);
  if (lane == 0) {
    const int em = emask[i * WW + j];
#pragma unroll
    for (int h = 0; h < H; ++h)
      biasT[((size_t)(h * WW + j)) * WW + i] = em ? acc[h] : NEGF;
  }
}

// ------- K3: xn @ [Wq | Wk | Wv | Wg] -> qkvg [32768 x 1024], sigmoid on g -------
__global__ __launch_bounds__(256) void k_qkvg(const float* __restrict__ xn,
                                              const float* __restrict__ Wq,
                                              const float* __restrict__ Wkv,
                                              const float* __restrict__ Wg,
                                              const float* __restrict__ bg,
                                              float* __restrict__ out) {
  __shared__ float As[16][68];   // [kk][m], padded
  __shared__ float Bs[16][68];   // [kk][n], padded
  const int bm = (blockIdx.x >> 4) << 6;   // 512 m-tiles
  const int bn = (blockIdx.x & 15) << 6;   // 16 n-tiles
  const int tid = threadIdx.x;
  const int tx = tid & 15, ty = tid >> 4;
  const int region = bn >> 8;              // 0:q 1:k 2:v 3:g
  const float* Bp; int ldb, bnl;
  if (region == 0)      { Bp = Wq;  ldb = 256; bnl = bn; }
  else if (region == 3) { Bp = Wg;  ldb = 256; bnl = bn - 768; }
  else                  { Bp = Wkv; ldb = 512; bnl = bn - 256; } // k and v both

  const int lm  = tid >> 2,        lkq = (tid & 3) << 2;   // A: row lm, k quad
  const int lkk = tid >> 4,        lnq = (tid & 15) << 2;  // B: k row, n quad

  float c[4][4] = {};
  for (int k0 = 0; k0 < DN; k0 += 16) {
    const float4 a4 = *(const float4*)(xn + (size_t)(bm + lm) * DN + k0 + lkq);
    const float4 b4 = *(const float4*)(Bp + (size_t)(k0 + lkk) * ldb + bnl + lnq);
    __syncthreads();
    As[lkq + 0][lm] = a4.x; As[lkq + 1][lm] = a4.y;
    As[lkq + 2][lm] = a4.z; As[lkq + 3][lm] = a4.w;
    *(float4*)&Bs[lkk][lnq] = b4;
    __syncthreads();
#pragma unroll
    for (int kk = 0; kk < 16; ++kk) {
      const float4 a  = *(const float4*)&As[kk][ty << 2];
      const float4 bv = *(const float4*)&Bs[kk][tx << 2];
      const float av[4]  = {a.x, a.y, a.z, a.w};
      const float bvv[4] = {bv.x, bv.y, bv.z, bv.w};
#pragma unroll
      for (int u = 0; u < 4; ++u)
#pragma unroll
        for (int v = 0; v < 4; ++v) c[u][v] += av[u] * bvv[v];
    }
  }
  const int colb = bn + (tx << 2);
#pragma unroll
  for (int u = 0; u < 4; ++u) {
    const int row = bm + (ty << 2) + u;
    float4 cv = make_float4(c[u][0], c[u][1], c[u][2], c[u][3]);
    if (region == 3) {
      const int cl = bnl + (tx << 2);
      cv.x = 1.f / (1.f + __expf(-(cv.x + bg[cl + 0])));
      cv.y = 1.f / (1.f + __expf(-(cv.y + bg[cl + 1])));
      cv.z = 1.f / (1.f + __expf(-(cv.z + bg[cl + 2])));
      cv.w = 1.f / (1.f + __expf(-(cv.w + bg[cl + 3])));
    }
    *(float4*)(out + (size_t)row * NQKVG + colb) = cv;
  }
}

// ------- K4: flash attention per (r,h); out = softmax(qk^T*s + bias) v * gate -------
__global__ __launch_bounds__(256) void k_attn(const float* __restrict__ qkvg,
                                              const float* __restrict__ biasT,
                                              const int* __restrict__ mask,
                                              float* __restrict__ aout) {
  __shared__ float ks[WW][DH];   // 32 KB
  __shared__ float vs[WW][DH];   // 32 KB
  __shared__ int ms[WW];
  const int r = blockIdx.x >> 3, h = blockIdx.x & 7;
  const int tid = threadIdx.x;
  const size_t rowbase = (size_t)r * WW;
#pragma unroll
  for (int p = 0; p < 8; ++p) {
    const int idx = (p << 8) + tid;          // 2048 float4 slots
    const int j = idx >> 3, dq = (idx & 7) << 2;
    const float* src = qkvg + (rowbase + j) * NQKVG + 256 + h * DH + dq;
    *(float4*)&ks[j][dq] = *(const float4*)src;
    *(float4*)&vs[j][dq] = *(const float4*)(src + 256);
  }
  ms[tid] = mask[r * WW + tid];
  __syncthreads();

  const int i = tid;
  float q[32];
  {
    const float4* qp = (const float4*)(qkvg + (rowbase + i) * NQKVG + h * DH);
#pragma unroll
    for (int p = 0; p < 8; ++p) *(float4*)&q[p << 2] = qp[p];
  }
  const int mi = ms[i];
  const float* bp = biasT + (size_t)(h * WW) * WW + i;  // bias[h][i][j] at bp[j*WW]
  const float scale = 0.17677669529663687f;             // 32^-0.5
  float m = NEGF, l = 0.f;
  float o[32] = {};

  for (int j = 0; j < WW; ++j) {
    float d0 = 0.f, d1 = 0.f, d2 = 0.f, d3 = 0.f;
#pragma unroll
    for (int d = 0; d < 32; d += 4) {
      d0 += q[d + 0] * ks[j][d + 0];
      d1 += q[d + 1] * ks[j][d + 1];
      d2 += q[d + 2] * ks[j][d + 2];
      d3 += q[d + 3] * ks[j][d + 3];
    }
    float s = (d0 + d1 + d2 + d3) * scale + bp[(size_t)j * WW];
    s = (mi && ms[j]) ? s : NEGF;
    if (s - m > 8.f) {            // defer-max (T13): rescale only on big jumps
      const float f = __expf(m - s);
      m = s; l *= f;
#pragma unroll
      for (int d = 0; d < 32; ++d) o[d] *= f;
    }
    const float pw = __expf(s - m);
    l += pw;
#pragma unroll
    for (int d = 0; d < 32; ++d) o[d] += pw * vs[j][d];
  }
  const float inv = 1.f / l;
  const float* gp = qkvg + (rowbase + i) * NQKVG + 768 + h * DH;
  float* op = aout + (rowbase + i) * DN + h * DH;
#pragma unroll
  for (int d = 0; d < 32; d += 4) {
    const float4 gv = *(const float4*)(gp + d);
    float4 ov;
    ov.x = o[d + 0] * inv * gv.x; ov.y = o[d + 1] * inv * gv.y;
    ov.z = o[d + 2] * inv * gv.z; ov.w = o[d + 3] * inv * gv.w;
    *(float4*)(op + d) = ov;
  }
}

// ------- K5: attnout @ Wo + bo -> out [32768 x 256] -------
__global__ __launch_bounds__(256) void k_out(const float* __restrict__ A,
                                             const float* __restrict__ Wo,
                                             const float* __restrict__ bo,
                                             float* __restrict__ out) {
  __shared__ float As[16][68];
  __shared__ float Bs[16][68];
  const int bm = (blockIdx.x >> 2) << 6;   // 512 m-tiles
  const int bn = (blockIdx.x & 3) << 6;    // 4 n-tiles
  const int tid = threadIdx.x;
  const int tx = tid & 15, ty = tid >> 4;
  const int lm  = tid >> 2, lkq = (tid & 3) << 2;
  const int lkk = tid >> 4, lnq = (tid & 15) << 2;

  float c[4][4] = {};
  for (int k0 = 0; k0 < DN; k0 += 16) {
    const float4 a4 = *(const float4*)(A  + (size_t)(bm + lm) * DN + k0 + lkq);
    const float4 b4 = *(const float4*)(Wo + (size_t)(k0 + lkk) * DN + bn + lnq);
    __syncthreads();
    As[lkq + 0][lm] = a4.x; As[lkq + 1][lm] = a4.y;
    As[lkq + 2][lm] = a4.z; As[lkq + 3][lm] = a4.w;
    *(float4*)&Bs[lkk][lnq] = b4;
    __syncthreads();
#pragma unroll
    for (int kk = 0; kk < 16; ++kk) {
      const float4 a  = *(const float4*)&As[kk][ty << 2];
      const float4 bv = *(const float4*)&Bs[kk][tx << 2];
      const float av[4]  = {a.x, a.y, a.z, a.w};
      const float bvv[4] = {bv.x, bv.y, bv.z, bv.w};
#pragma unroll
      for (int u = 0; u < 4; ++u)
#pragma unroll
        for (int v = 0; v < 4; ++v) c[u][v] += av[u] * bvv[v];
    }
  }
  const int colb = bn + (tx << 2);
#pragma unroll
  for (int u = 0; u < 4; ++u) {
    const int row = bm + (ty << 2) + u;
    float4 cv = make_float4(c[u][0] + bo[colb + 0], c[u][1] + bo[colb + 1],
                            c[u][2] + bo[colb + 2], c[u][3] + bo[colb + 3]);
    *(float4*)(out + (size_t)row * DN + colb) = cv;
  }
}

extern "C" void kernel_launch(void* const* d_in, const int* in_sizes, int n_in,
                              void* d_out, int out_size, void* d_ws, size_t ws_size,
                              hipStream_t stream) {
  const float* x      = (const float*)d_in[0];
  const float* edges  = (const float*)d_in[1];
  const int*   mask   = (const int*)d_in[2];
  const int*   emask  = (const int*)d_in[3];
  const float* ln_g   = (const float*)d_in[4];
  const float* ln_b   = (const float*)d_in[5];
  const float* lne_g  = (const float*)d_in[6];
  const float* lne_b  = (const float*)d_in[7];
  const float* W_edge = (const float*)d_in[8];
  const float* Wq     = (const float*)d_in[9];
  const float* Wkv    = (const float*)d_in[10];
  const float* Wg     = (const float*)d_in[11];
  const float* bg     = (const float*)d_in[12];
  const float* Wo     = (const float*)d_in[13];
  const float* bo     = (const float*)d_in[14];
  float* out = (float*)d_out;

  // Workspace layout (floats): qkvg 33.5M | biasT 0.5M | aout 8.4M  => ~137 MB
  float* ws    = (float*)d_ws;
  float* qkvg  = ws;                              // 33,554,432 floats
  float* biasT = qkvg + 33554432;                 //    524,288 floats
  float* aout  = biasT + 524288;                  //  8,388,608 floats
  float* xn    = out;                             // d_out doubles as xn scratch;
                                                  // dead before k_out writes out.

  k_ln_x<<<MROWS / 4, 256, 0, stream>>>(x, ln_g, ln_b, xn);
  k_bias<<<(WW * WW) / 4, 256, 0, stream>>>(edges, emask, lne_g, lne_b, W_edge, biasT);
  k_qkvg<<<(MROWS / 64) * 16, 256, 0, stream>>>(xn, Wq, Wkv, Wg, bg, qkvg);
  k_attn<<<RR * H, 256, 0, stream>>>(qkvg, biasT, mask, aout);
  k_out<<<(MROWS / 64) * 4, 256, 0, stream>>>(aout, Wo, bo, out);
}

// Round 3
// 479.281 us; speedup vs baseline: 1.4071x; 1.4071x over previous
//
#include <hip/hip_runtime.h>

#define NEGF (-3.402823466e38f)

constexpr int H  = 8,  DH = 32, DN = 256, DE = 128;
constexpr int RR = 128, WW = 256;
constexpr int MROWS = RR * WW;     // 32768 token rows

typedef __attribute__((ext_vector_type(8))) short bf16x8;
typedef __attribute__((ext_vector_type(4))) short bf16x4;
typedef __attribute__((ext_vector_type(4))) float f32x4;

__device__ __forceinline__ float b2f(short s) {
  unsigned u = ((unsigned)(unsigned short)s) << 16;
  return __builtin_bit_cast(float, u);
}
__device__ __forceinline__ short f2b(float f) {   // round-to-nearest-even
  unsigned u = __builtin_bit_cast(unsigned, f);
  unsigned r = (u + 0x7fffu + ((u >> 16) & 1u)) >> 16;
  return (short)r;
}
__device__ __forceinline__ float wred(float v) {
#pragma unroll
  for (int off = 32; off > 0; off >>= 1) v += __shfl_xor(v, off, 64);
  return v;
}

// ---------------- K1: LayerNorm(x) -> xnb (bf16) [32768 x 256] ----------------
__global__ __launch_bounds__(256) void k_ln_x(const float* __restrict__ x,
                                              const float* __restrict__ g,
                                              const float* __restrict__ b,
                                              short* __restrict__ xnb) {
  const int wave = threadIdx.x >> 6, lane = threadIdx.x & 63;
  const int row = (blockIdx.x << 2) + wave;
  const float4 v = ((const float4*)(x + (size_t)row * DN))[lane];
  float s  = v.x + v.y + v.z + v.w;
  float s2 = v.x*v.x + v.y*v.y + v.z*v.z + v.w*v.w;
  s = wred(s); s2 = wred(s2);
  const float mu = s * (1.f / DN);
  const float rs = rsqrtf(s2 * (1.f / DN) - mu * mu + 1e-5f);
  const float4 gg = ((const float4*)g)[lane];
  const float4 bb = ((const float4*)b)[lane];
  bf16x4 o;
  o[0] = f2b((v.x - mu) * rs * gg.x + bb.x);
  o[1] = f2b((v.y - mu) * rs * gg.y + bb.y);
  o[2] = f2b((v.z - mu) * rs * gg.z + bb.z);
  o[3] = f2b((v.w - mu) * rs * gg.w + bb.w);
  ((bf16x4*)(xnb + (size_t)row * DN))[lane] = o;
}

// ---- K1b: cast+transpose weights -> wt bf16: [0,262144) = WqkvgT[1024][256],
// ----      [262144,327680) = WoT[256][256]
__global__ __launch_bounds__(256) void k_prep(const float* __restrict__ Wq,
                                              const float* __restrict__ Wkv,
                                              const float* __restrict__ Wg,
                                              const float* __restrict__ Wo,
                                              short* __restrict__ wt) {
  const int idx = blockIdx.x * 256 + threadIdx.x;
  if (idx < 262144) {
    const int n = idx >> 8, k = idx & 255;
    float v;
    if (n < 256)      v = Wq[k * 256 + n];
    else if (n < 768) v = Wkv[k * 512 + (n - 256)];   // k cols 0-255, v cols 256-511
    else              v = Wg[k * 256 + (n - 768)];
    wt[idx] = f2b(v);
  } else {
    const int m = idx - 262144;
    const int n = m >> 8, k = m & 255;
    wt[idx] = f2b(Wo[k * 256 + n]);
  }
}

// ------- K2: LayerNorm(edges) @ W_edge -> biasT[h][j][i] (fp32), edge-masked -------
__global__ __launch_bounds__(256) void k_bias(const float* __restrict__ edges,
                                              const int* __restrict__ emask,
                                              const float* __restrict__ g,
                                              const float* __restrict__ b,
                                              const float* __restrict__ We,
                                              float* __restrict__ biasT) {
  const int wave = threadIdx.x >> 6, lane = threadIdx.x & 63;
  const int p = (blockIdx.x << 2) + wave;   // p = j*WW + i
  const int i = p & (WW - 1), j = p >> 8;
  const float2 e = ((const float2*)(edges + (size_t)(i * WW + j) * DE))[lane];
  float s = e.x + e.y, s2 = e.x*e.x + e.y*e.y;
  s = wred(s); s2 = wred(s2);
  const float mu = s * (1.f / DE);
  const float rs = rsqrtf(s2 * (1.f / DE) - mu * mu + 1e-5f);
  const float2 gg = ((const float2*)g)[lane];
  const float2 bb = ((const float2*)b)[lane];
  const float n0 = (e.x - mu) * rs * gg.x + bb.x;
  const float n1 = (e.y - mu) * rs * gg.y + bb.y;
  const float* w0 = We + (lane * 2) * H;
  float acc[H];
#pragma unroll
  for (int h = 0; h < H; ++h) acc[h] = n0 * w0[h] + n1 * w0[H + h];
#pragma unroll
  for (int off = 32; off > 0; off >>= 1)
#pragma unroll
    for (int h = 0; h < H; ++h) acc[h] += __shfl_xor(acc[h], off, 64);
  if (lane == 0) {
    const int em = emask[i * WW + j];
#pragma unroll
    for (int h = 0; h < H; ++h)
      biasT[((size_t)(h * WW + j)) * WW + i] = em ? acc[h] : NEGF;
  }
}

// ------- K3/K5: bf16 MFMA GEMM, C[M,N] = A[M,256] @ Bt[N,256]^T -------
// 128x128 tile, 4 waves (2x2 of 64x64), BK=64, global_load_lds staging.
// EPI 0: sigmoid(v+bg) on cols>=768, bf16 out (N=1024).  EPI 1: v+bias, f32 out.
template<int N, int EPI>
__global__ __launch_bounds__(256) void k_gemm(const short* __restrict__ A,
                                              const short* __restrict__ Bt,
                                              const float* __restrict__ bias,
                                              void* __restrict__ Cout) {
  __shared__ short As[128 * 64];
  __shared__ short Bs[128 * 64];
  const int tid = threadIdx.x;
  const int w = tid >> 6, lane = tid & 63;
  constexpr int nb = N / 128;
  const int bm = (blockIdx.x / nb) * 128;
  const int bn = (blockIdx.x % nb) * 128;
  const int wm = w >> 1, wn = w & 1;

  const int sr0 = (w << 5) + (lane >> 3);     // staging row (+ q*8)
  const int sc  = (lane & 7) << 3;            // staging col (8 bf16 = 16B)

  f32x4 acc[4][4] = {};

  for (int k0 = 0; k0 < 256; k0 += 64) {
    __syncthreads();                          // prev-iter LDS reads done
#pragma unroll
    for (int q = 0; q < 4; ++q) {
      const int row = sr0 + (q << 3);
      const short* ga = A  + (size_t)(bm + row) * 256 + k0 + sc;
      const short* gb = Bt + (size_t)(bn + row) * 256 + k0 + sc;
      const int la = (w << 12) + (q << 10);   // wave-uniform LDS byte base
      __builtin_amdgcn_global_load_lds(
          (const __attribute__((address_space(1))) void*)ga,
          (__attribute__((address_space(3))) void*)((__attribute__((address_space(3))) char*)As + la),
          16, 0, 0);
      __builtin_amdgcn_global_load_lds(
          (const __attribute__((address_space(1))) void*)gb,
          (__attribute__((address_space(3))) void*)((__attribute__((address_space(3))) char*)Bs + la),
          16, 0, 0);
    }
    asm volatile("s_waitcnt vmcnt(0)" ::: "memory");
    __syncthreads();                          // all waves' tiles resident
#pragma unroll
    for (int ks = 0; ks < 2; ++ks) {
      const int kk = (ks << 5) + ((lane >> 4) << 3);
      bf16x8 af[4], bfr[4];
#pragma unroll
      for (int f = 0; f < 4; ++f) {
        const int ar = (wm << 6) + (f << 4) + (lane & 15);
        const int br = (wn << 6) + (f << 4) + (lane & 15);
        af[f]  = *(const bf16x8*)&As[ar * 64 + kk];
        bfr[f] = *(const bf16x8*)&Bs[br * 64 + kk];
      }
#pragma unroll
      for (int mi = 0; mi < 4; ++mi)
#pragma unroll
        for (int ni = 0; ni < 4; ++ni)
          acc[mi][ni] = __builtin_amdgcn_mfma_f32_16x16x32_bf16(
              af[mi], bfr[ni], acc[mi][ni], 0, 0, 0);
    }
  }

  const int r0 = bm + (wm << 6) + ((lane >> 4) << 2);   // + mi*16 + jj
  const int c0 = bn + (wn << 6) + (lane & 15);          // + ni*16
#pragma unroll
  for (int mi = 0; mi < 4; ++mi)
#pragma unroll
    for (int ni = 0; ni < 4; ++ni) {
      const int col = c0 + ni * 16;
      if (EPI == 0) {
        short* C = (short*)Cout;
        const bool gate = (bn + wn * 64 + ni * 16) >= 768;   // uniform per frag
        const float bgv = gate ? bias[col - 768] : 0.f;
#pragma unroll
        for (int jj = 0; jj < 4; ++jj) {
          float v = acc[mi][ni][jj];
          if (gate) v = 1.f / (1.f + __expf(-(v + bgv)));
          C[(size_t)(r0 + mi * 16 + jj) * N + col] = f2b(v);
        }
      } else {
        float* C = (float*)Cout;
        const float bv = bias[col];
#pragma unroll
        for (int jj = 0; jj < 4; ++jj)
          C[(size_t)(r0 + mi * 16 + jj) * N + col] = acc[mi][ni][jj] + bv;
      }
    }
}

// ------- K4: flash attention per (r,h); qkvg bf16 in, aout bf16 out -------
__global__ __launch_bounds__(256) void k_attn(const short* __restrict__ qkvg,
                                              const float* __restrict__ biasT,
                                              const int* __restrict__ mask,
                                              short* __restrict__ aout) {
  __shared__ float ksh[WW][36];   // stride 36 breaks write conflicts; ~36.9 KB
  __shared__ int ms[WW];
  const int r = blockIdx.x >> 3, h = blockIdx.x & 7;
  const int tid = threadIdx.x;
  const size_t rowbase = (size_t)r * WW;

  // stage K (bf16 -> f32), coalesced 16B chunks
#pragma unroll
  for (int p = 0; p < 4; ++p) {
    const int f8 = (p << 8) + tid;
    const int row = f8 >> 2, dq = (f8 & 3) << 3;
    const bf16x8 kv = *(const bf16x8*)(qkvg + (rowbase + row) * 1024 + 256 + h * 32 + dq);
#pragma unroll
    for (int e = 0; e < 8; e += 4) {
      float4 f;
      f.x = b2f(kv[e]); f.y = b2f(kv[e + 1]); f.z = b2f(kv[e + 2]); f.w = b2f(kv[e + 3]);
      *(float4*)&ksh[row][dq + e] = f;
    }
  }
  ms[tid] = mask[r * WW + tid];
  __syncthreads();

  const int i = tid, mi = ms[i];
  float q[32];
  {
    const short* qp = qkvg + (rowbase + i) * 1024 + h * 32;
#pragma unroll
    for (int p = 0; p < 4; ++p) {
      const bf16x8 v = *(const bf16x8*)(qp + (p << 3));
#pragma unroll
      for (int e = 0; e < 8; ++e) q[(p << 3) + e] = b2f(v[e]);
    }
  }
  const float* bp = biasT + ((size_t)h << 16) + i;
  const short* vbase = qkvg + rowbase * 1024 + 512 + h * 32;
  const float scale = 0.17677669529663687f;
  float m = NEGF, l = 0.f;
  float o[32] = {};

  for (int j = 0; j < WW; j += 2) {
    const float bb0 = bp[(size_t)j << 8];
    const float bb1 = bp[(size_t)(j + 1) << 8];
    float a0 = 0, a1 = 0, a2 = 0, a3 = 0, c0 = 0, c1 = 0, c2 = 0, c3 = 0;
#pragma unroll
    for (int d = 0; d < 32; d += 4) {
      a0 += q[d + 0] * ksh[j][d + 0];     a1 += q[d + 1] * ksh[j][d + 1];
      a2 += q[d + 2] * ksh[j][d + 2];     a3 += q[d + 3] * ksh[j][d + 3];
      c0 += q[d + 0] * ksh[j + 1][d + 0]; c1 += q[d + 1] * ksh[j + 1][d + 1];
      c2 += q[d + 2] * ksh[j + 1][d + 2]; c3 += q[d + 3] * ksh[j + 1][d + 3];
    }
    float s0 = (a0 + a1 + a2 + a3) * scale + bb0;
    float s1 = (c0 + c1 + c2 + c3) * scale + bb1;
    s0 = (mi && ms[j])     ? s0 : NEGF;
    s1 = (mi && ms[j + 1]) ? s1 : NEGF;
    const float mx = fmaxf(s0, s1);
    if (mx - m > 8.f) {                 // defer-max (T13)
      const float f = __expf(m - mx);
      m = mx; l *= f;
#pragma unroll
      for (int d = 0; d < 32; ++d) o[d] *= f;
    }
    const float p0 = __expf(s0 - m), p1 = __expf(s1 - m);
    l += p0 + p1;
    const short* v0p = vbase + (size_t)j * 1024;
    const short* v1p = v0p + 1024;
#pragma unroll
    for (int c = 0; c < 4; ++c) {
      const bf16x8 v0 = *(const bf16x8*)(v0p + (c << 3));
      const bf16x8 v1 = *(const bf16x8*)(v1p + (c << 3));
#pragma unroll
      for (int e = 0; e < 8; ++e) {
        const int d = (c << 3) + e;
        o[d] += p0 * b2f(v0[e]);
        o[d] += p1 * b2f(v1[e]);
      }
    }
  }
  const float inv = 1.f / l;
  const short* gp = qkvg + (rowbase + i) * 1024 + 768 + h * 32;
  short* op = aout + (rowbase + i) * 256 + h * 32;
#pragma unroll
  for (int c = 0; c < 4; ++c) {
    const bf16x8 gv = *(const bf16x8*)(gp + (c << 3));
    bf16x8 ov;
#pragma unroll
    for (int e = 0; e < 8; ++e)
      ov[e] = f2b(o[(c << 3) + e] * inv * b2f(gv[e]));
    *(bf16x8*)(op + (c << 3)) = ov;
  }
}

extern "C" void kernel_launch(void* const* d_in, const int* in_sizes, int n_in,
                              void* d_out, int out_size, void* d_ws, size_t ws_size,
                              hipStream_t stream) {
  const float* x      = (const float*)d_in[0];
  const float* edges  = (const float*)d_in[1];
  const int*   mask   = (const int*)d_in[2];
  const int*   emask  = (const int*)d_in[3];
  const float* ln_g   = (const float*)d_in[4];
  const float* ln_b   = (const float*)d_in[5];
  const float* lne_g  = (const float*)d_in[6];
  const float* lne_b  = (const float*)d_in[7];
  const float* W_edge = (const float*)d_in[8];
  const float* Wq     = (const float*)d_in[9];
  const float* Wkv    = (const float*)d_in[10];
  const float* Wg     = (const float*)d_in[11];
  const float* bg     = (const float*)d_in[12];
  const float* Wo     = (const float*)d_in[13];
  const float* bo     = (const float*)d_in[14];
  float* out = (float*)d_out;

  // ws layout (bytes): qkvgb 67,108,864 | xnb 16,777,216 | aoutb 16,777,216 |
  //                    wt 655,360 | biasT 2,097,152   => ~98.6 MB total
  char*  ws    = (char*)d_ws;
  short* qkvgb = (short*)ws;
  short* xnb   = (short*)(ws + 67108864);
  short* aoutb = (short*)(ws + 67108864 + 16777216);
  short* wt    = (short*)(ws + 100663296);
  float* biasT = (float*)(ws + 101318656);

  k_ln_x<<<MROWS / 4, 256, 0, stream>>>(x, ln_g, ln_b, xnb);
  k_prep<<<1280, 256, 0, stream>>>(Wq, Wkv, Wg, Wo, wt);
  k_bias<<<(WW * WW) / 4, 256, 0, stream>>>(edges, emask, lne_g, lne_b, W_edge, biasT);
  k_gemm<1024, 0><<<(MROWS / 128) * 8, 256, 0, stream>>>(xnb, wt, bg, (void*)qkvgb);
  k_attn<<<RR * H, 256, 0, stream>>>(qkvgb, biasT, mask, aoutb);
  k_gemm<256, 1><<<(MROWS / 128) * 2, 256, 0, stream>>>(aoutb, wt + 262144, bo, (void*)out);
}

// Round 4
// 282.196 us; speedup vs baseline: 2.3898x; 1.6984x over previous
//
#include <hip/hip_runtime.h>

#define NEGF (-3.402823466e38f)

constexpr int H  = 8,  DH = 32, DN = 256, DE = 128;
constexpr int RR = 128, WW = 256;
constexpr int MROWS = RR * WW;     // 32768 token rows

typedef __attribute__((ext_vector_type(8))) short bf16x8;
typedef __attribute__((ext_vector_type(4))) short bf16x4;
typedef __attribute__((ext_vector_type(4))) float f32x4;

__device__ __forceinline__ float b2f(short s) {
  unsigned u = ((unsigned)(unsigned short)s) << 16;
  return __builtin_bit_cast(float, u);
}
__device__ __forceinline__ short f2b(float f) {   // round-to-nearest-even
  unsigned u = __builtin_bit_cast(unsigned, f);
  unsigned r = (u + 0x7fffu + ((u >> 16) & 1u)) >> 16;
  return (short)r;
}
__device__ __forceinline__ float wred(float v) {
#pragma unroll
  for (int off = 32; off > 0; off >>= 1) v += __shfl_xor(v, off, 64);
  return v;
}

// ---------------- K1: LayerNorm(x) -> xnb (bf16) [32768 x 256] ----------------
__global__ __launch_bounds__(256) void k_ln_x(const float* __restrict__ x,
                                              const float* __restrict__ g,
                                              const float* __restrict__ b,
                                              short* __restrict__ xnb) {
  const int wave = threadIdx.x >> 6, lane = threadIdx.x & 63;
  const int row = (blockIdx.x << 2) + wave;
  const float4 v = ((const float4*)(x + (size_t)row * DN))[lane];
  float s  = v.x + v.y + v.z + v.w;
  float s2 = v.x*v.x + v.y*v.y + v.z*v.z + v.w*v.w;
  s = wred(s); s2 = wred(s2);
  const float mu = s * (1.f / DN);
  const float rs = rsqrtf(s2 * (1.f / DN) - mu * mu + 1e-5f);
  const float4 gg = ((const float4*)g)[lane];
  const float4 bb = ((const float4*)b)[lane];
  bf16x4 o;
  o[0] = f2b((v.x - mu) * rs * gg.x + bb.x);
  o[1] = f2b((v.y - mu) * rs * gg.y + bb.y);
  o[2] = f2b((v.z - mu) * rs * gg.z + bb.z);
  o[3] = f2b((v.w - mu) * rs * gg.w + bb.w);
  ((bf16x4*)(xnb + (size_t)row * DN))[lane] = o;
}

// ---- K1b: cast+transpose weights -> wt bf16: [0,262144) = WqkvgT[1024][256],
// ----      [262144,327680) = WoT[256][256]
__global__ __launch_bounds__(256) void k_prep(const float* __restrict__ Wq,
                                              const float* __restrict__ Wkv,
                                              const float* __restrict__ Wg,
                                              const float* __restrict__ Wo,
                                              short* __restrict__ wt) {
  const int idx = blockIdx.x * 256 + threadIdx.x;
  if (idx < 262144) {
    const int n = idx >> 8, k = idx & 255;
    float v;
    if (n < 256)      v = Wq[k * 256 + n];
    else if (n < 768) v = Wkv[k * 512 + (n - 256)];   // k cols 0-255, v cols 256-511
    else              v = Wg[k * 256 + (n - 768)];
    wt[idx] = f2b(v);
  } else {
    const int m = idx - 262144;
    const int n = m >> 8, k = m & 255;
    wt[idx] = f2b(Wo[k * 256 + n]);
  }
}

// ------- K2: LayerNorm(edges)@W_edge -> bias2[h][j>>2][q][j&3] (f32), masked -------
__global__ __launch_bounds__(256) void k_bias(const float* __restrict__ edges,
                                              const int* __restrict__ emask,
                                              const float* __restrict__ g,
                                              const float* __restrict__ b,
                                              const float* __restrict__ We,
                                              float* __restrict__ bias2) {
  const int wave = threadIdx.x >> 6, lane = threadIdx.x & 63;
  const int p = (blockIdx.x << 2) + wave;   // p = j*WW + i
  const int i = p & (WW - 1), j = p >> 8;
  const float2 e = ((const float2*)(edges + (size_t)(i * WW + j) * DE))[lane];
  float s = e.x + e.y, s2 = e.x*e.x + e.y*e.y;
  s = wred(s); s2 = wred(s2);
  const float mu = s * (1.f / DE);
  const float rs = rsqrtf(s2 * (1.f / DE) - mu * mu + 1e-5f);
  const float2 gg = ((const float2*)g)[lane];
  const float2 bb = ((const float2*)b)[lane];
  const float n0 = (e.x - mu) * rs * gg.x + bb.x;
  const float n1 = (e.y - mu) * rs * gg.y + bb.y;
  const float* w0 = We + (lane * 2) * H;
  float acc[H];
#pragma unroll
  for (int h = 0; h < H; ++h) acc[h] = n0 * w0[h] + n1 * w0[H + h];
#pragma unroll
  for (int off = 32; off > 0; off >>= 1)
#pragma unroll
    for (int h = 0; h < H; ++h) acc[h] += __shfl_xor(acc[h], off, 64);
  if (lane == 0) {
    const int em = emask[i * WW + j];
#pragma unroll
    for (int h = 0; h < H; ++h)
      bias2[(size_t)((h << 6) + (j >> 2)) * 1024 + (i << 2) + (j & 3)]
          = em ? acc[h] : NEGF;
  }
}

// ------- K3/K5: bf16 MFMA GEMM, C[M,N] = A[M,256] @ Bt[N,256]^T -------
template<int N, int EPI>
__global__ __launch_bounds__(256) void k_gemm(const short* __restrict__ A,
                                              const short* __restrict__ Bt,
                                              const float* __restrict__ bias,
                                              void* __restrict__ Cout) {
  __shared__ short As[128 * 64];
  __shared__ short Bs[128 * 64];
  const int tid = threadIdx.x;
  const int w = tid >> 6, lane = tid & 63;
  constexpr int nb = N / 128;
  const int bm = (blockIdx.x / nb) * 128;
  const int bn = (blockIdx.x % nb) * 128;
  const int wm = w >> 1, wn = w & 1;

  const int sr0 = (w << 5) + (lane >> 3);     // staging row (+ q*8)
  const int sc  = (lane & 7) << 3;            // staging col (8 bf16 = 16B)

  f32x4 acc[4][4] = {};

  for (int k0 = 0; k0 < 256; k0 += 64) {
    __syncthreads();                          // prev-iter LDS reads done
#pragma unroll
    for (int q = 0; q < 4; ++q) {
      const int row = sr0 + (q << 3);
      const short* ga = A  + (size_t)(bm + row) * 256 + k0 + sc;
      const short* gb = Bt + (size_t)(bn + row) * 256 + k0 + sc;
      const int la = (w << 12) + (q << 10);   // wave-uniform LDS byte base
      __builtin_amdgcn_global_load_lds(
          (const __attribute__((address_space(1))) void*)ga,
          (__attribute__((address_space(3))) void*)((__attribute__((address_space(3))) char*)As + la),
          16, 0, 0);
      __builtin_amdgcn_global_load_lds(
          (const __attribute__((address_space(1))) void*)gb,
          (__attribute__((address_space(3))) void*)((__attribute__((address_space(3))) char*)Bs + la),
          16, 0, 0);
    }
    asm volatile("s_waitcnt vmcnt(0)" ::: "memory");
    __syncthreads();                          // all waves' tiles resident
#pragma unroll
    for (int ks = 0; ks < 2; ++ks) {
      const int kk = (ks << 5) + ((lane >> 4) << 3);
      bf16x8 af[4], bfr[4];
#pragma unroll
      for (int f = 0; f < 4; ++f) {
        const int ar = (wm << 6) + (f << 4) + (lane & 15);
        const int br = (wn << 6) + (f << 4) + (lane & 15);
        af[f]  = *(const bf16x8*)&As[ar * 64 + kk];
        bfr[f] = *(const bf16x8*)&Bs[br * 64 + kk];
      }
#pragma unroll
      for (int mi = 0; mi < 4; ++mi)
#pragma unroll
        for (int ni = 0; ni < 4; ++ni)
          acc[mi][ni] = __builtin_amdgcn_mfma_f32_16x16x32_bf16(
              af[mi], bfr[ni], acc[mi][ni], 0, 0, 0);
    }
  }

  const int r0 = bm + (wm << 6) + ((lane >> 4) << 2);   // + mi*16 + jj
  const int c0 = bn + (wn << 6) + (lane & 15);          // + ni*16
#pragma unroll
  for (int mi = 0; mi < 4; ++mi)
#pragma unroll
    for (int ni = 0; ni < 4; ++ni) {
      const int col = c0 + ni * 16;
      if (EPI == 0) {
        short* C = (short*)Cout;
        const bool gate = (bn + wn * 64 + ni * 16) >= 768;   // uniform per frag
        const float bgv = gate ? bias[col - 768] : 0.f;
#pragma unroll
        for (int jj = 0; jj < 4; ++jj) {
          float v = acc[mi][ni][jj];
          if (gate) v = 1.f / (1.f + __expf(-(v + bgv)));
          C[(size_t)(r0 + mi * 16 + jj) * N + col] = f2b(v);
        }
      } else {
        float* C = (float*)Cout;
        const float bv = bias[col];
#pragma unroll
        for (int jj = 0; jj < 4; ++jj)
          C[(size_t)(r0 + mi * 16 + jj) * N + col] = acc[mi][ni][jj] + bv;
      }
    }
}

// ------- K4: MFMA flash attention per (r,h) -------
// Swapped QK^T: S^T tiles = mfma(A=K, B=Q) -> q on lane&15 (softmax lane-local-ish).
// PV uses permuted-k: A=P packed [jt0 r0..3 | jt1 r0..3], B=V read with same perm.
__global__ __launch_bounds__(256) void k_attn(const short* __restrict__ qkvg,
                                              const float* __restrict__ bias2,
                                              const int* __restrict__ mask,
                                              short* __restrict__ aout) {
  __shared__ short K_lds[256 * 40];   // [j][40] pad: conflict-free b128 reads
  __shared__ short VT_lds[32 * 260];  // [d][260] transposed V
  __shared__ float jm_lds[256];       // additive row-mask: 0 or NEGF
  const int r = blockIdx.x >> 3, h = blockIdx.x & 7;
  const int tid = threadIdx.x;
  const int w = tid >> 6, lane = tid & 63;
  const int g = lane >> 4, c = lane & 15;
  const size_t rowbase = (size_t)r * WW;

  // ---- stage K, V^T, mask ----
  {
    const int jr = tid >> 2, ch = (tid & 3) << 3;
#pragma unroll
    for (int p = 0; p < 4; ++p) {
      const int j = (p << 6) + jr;
      const short* src = qkvg + (rowbase + j) * 1024 + 256 + h * 32 + ch;
      *(bf16x8*)&K_lds[j * 40 + ch] = *(const bf16x8*)src;
      const bf16x8 vv = *(const bf16x8*)(src + 256);
#pragma unroll
      for (int e = 0; e < 8; ++e) VT_lds[(ch + e) * 260 + j] = vv[e];
    }
    jm_lds[tid] = mask[r * WW + tid] ? 0.f : NEGF;
  }
  __syncthreads();

  // ---- per-wave state: q in [64w, 64w+64) ----
  const int q0 = (w << 6);
  bf16x8 qf[4];
  float qm[4];
#pragma unroll
  for (int qt = 0; qt < 4; ++qt) {
    qf[qt] = *(const bf16x8*)(qkvg + (rowbase + q0 + (qt << 4) + c) * 1024 + h * 32 + (g << 3));
    qm[qt] = jm_lds[q0 + (qt << 4) + c];
  }
  float m[4] = {NEGF, NEGF, NEGF, NEGF}, l[4] = {};
  f32x4 O[4][2] = {};
  const float scale = 0.17677669529663687f;   // 32^-0.5
  const float* bh = bias2 + ((size_t)h << 16);

  for (int jb = 0; jb < WW; jb += 32) {
    // K A-frags (j-rows on lane&15), jm vectors
    const bf16x8 kf0 = *(const bf16x8*)&K_lds[(jb + c) * 40 + (g << 3)];
    const bf16x8 kf1 = *(const bf16x8*)&K_lds[(jb + 16 + c) * 40 + (g << 3)];
    const f32x4 jm0 = *(const f32x4*)&jm_lds[jb + (g << 2)];
    const f32x4 jm1 = *(const f32x4*)&jm_lds[jb + 16 + (g << 2)];
    // S^T tiles + bias + mask
    f32x4 s[4][2];
    float pmax[4];
#pragma unroll
    for (int qt = 0; qt < 4; ++qt) {
      const f32x4 z = {0.f, 0.f, 0.f, 0.f};
      s[qt][0] = __builtin_amdgcn_mfma_f32_16x16x32_bf16(kf0, qf[qt], z, 0, 0, 0);
      s[qt][1] = __builtin_amdgcn_mfma_f32_16x16x32_bf16(kf1, qf[qt], z, 0, 0, 0);
      const int qq = q0 + (qt << 4) + c;
      const f32x4 bv0 = *(const f32x4*)(bh + (size_t)((jb >> 2) + (g)) * 1024 + (qq << 2));
      const f32x4 bv1 = *(const f32x4*)(bh + (size_t)((jb >> 2) + 4 + (g)) * 1024 + (qq << 2));
      float pm = NEGF;
#pragma unroll
      for (int rr = 0; rr < 4; ++rr) {
        float t0 = fmaxf(fmaf(s[qt][0][rr], scale, bv0[rr]) + jm0[rr] + qm[qt], NEGF);
        float t1 = fmaxf(fmaf(s[qt][1][rr], scale, bv1[rr]) + jm1[rr] + qm[qt], NEGF);
        s[qt][0][rr] = t0; s[qt][1][rr] = t1;
        pm = fmaxf(pm, fmaxf(t0, t1));
      }
      pm = fmaxf(pm, __shfl_xor(pm, 16, 64));
      pm = fmaxf(pm, __shfl_xor(pm, 32, 64));
      pmax[qt] = pm;
    }
    // defer-max rescale (rare)
    int need = 0;
#pragma unroll
    for (int qt = 0; qt < 4; ++qt) need |= (pmax[qt] > m[qt] + 8.f);
    if (__any(need)) {
      float fr[4];
#pragma unroll
      for (int qt = 0; qt < 4; ++qt) {
        const float mn = fmaxf(m[qt], pmax[qt]);
        fr[qt] = __expf(m[qt] - mn);
        m[qt] = mn; l[qt] *= fr[qt];
      }
#pragma unroll
      for (int qt = 0; qt < 4; ++qt)
#pragma unroll
        for (int rr = 0; rr < 4; ++rr) {
          const float fb = __shfl(fr[qt], (g << 2) | rr, 64);
          O[qt][0][rr] *= fb; O[qt][1][rr] *= fb;
        }
    }
    // exp, l-accumulate, pack P (A-frag order: [jt0 r0..3 | jt1 r0..3])
    bf16x8 pa[4];
#pragma unroll
    for (int qt = 0; qt < 4; ++qt) {
      float sum = 0.f;
#pragma unroll
      for (int rr = 0; rr < 4; ++rr) {
        const float e0 = __expf(s[qt][0][rr] - m[qt]);
        const float e1 = __expf(s[qt][1][rr] - m[qt]);
        sum += e0 + e1;
        pa[qt][rr] = f2b(e0);
        pa[qt][rr + 4] = f2b(e1);
      }
      sum += __shfl_xor(sum, 16, 64);
      sum += __shfl_xor(sum, 32, 64);
      l[qt] += sum;
    }
    // V B-frags with matching k-permutation
    bf16x8 vf[2];
#pragma unroll
    for (int dt = 0; dt < 2; ++dt) {
      const int dd = (dt << 4) + c;
      const bf16x4 lo = *(const bf16x4*)&VT_lds[dd * 260 + jb + (g << 2)];
      const bf16x4 hi = *(const bf16x4*)&VT_lds[dd * 260 + jb + 16 + (g << 2)];
      vf[dt] = __builtin_shufflevector(lo, hi, 0, 1, 2, 3, 4, 5, 6, 7);
    }
#pragma unroll
    for (int qt = 0; qt < 4; ++qt)
#pragma unroll
      for (int dt = 0; dt < 2; ++dt)
        O[qt][dt] = __builtin_amdgcn_mfma_f32_16x16x32_bf16(pa[qt], vf[dt], O[qt][dt], 0, 0, 0);
  }

  // ---- epilogue: O * (1/l) * gate -> aout ----
  float inv[4];
#pragma unroll
  for (int qt = 0; qt < 4; ++qt) inv[qt] = 1.f / l[qt];
#pragma unroll
  for (int qt = 0; qt < 4; ++qt)
#pragma unroll
    for (int rr = 0; rr < 4; ++rr) {
      const float iv = __shfl(inv[qt], (g << 2) | rr, 64);
      const size_t row = rowbase + q0 + (qt << 4) + (g << 2) + rr;
#pragma unroll
      for (int dt = 0; dt < 2; ++dt) {
        const int d = (dt << 4) + c;
        const float gate = b2f(qkvg[row * 1024 + 768 + h * 32 + d]);
        aout[row * 256 + h * 32 + d] = f2b(O[qt][dt][rr] * iv * gate);
      }
    }
}

extern "C" void kernel_launch(void* const* d_in, const int* in_sizes, int n_in,
                              void* d_out, int out_size, void* d_ws, size_t ws_size,
                              hipStream_t stream) {
  const float* x      = (const float*)d_in[0];
  const float* edges  = (const float*)d_in[1];
  const int*   mask   = (const int*)d_in[2];
  const int*   emask  = (const int*)d_in[3];
  const float* ln_g   = (const float*)d_in[4];
  const float* ln_b   = (const float*)d_in[5];
  const float* lne_g  = (const float*)d_in[6];
  const float* lne_b  = (const float*)d_in[7];
  const float* W_edge = (const float*)d_in[8];
  const float* Wq     = (const float*)d_in[9];
  const float* Wkv    = (const float*)d_in[10];
  const float* Wg     = (const float*)d_in[11];
  const float* bg     = (const float*)d_in[12];
  const float* Wo     = (const float*)d_in[13];
  const float* bo     = (const float*)d_in[14];
  float* out = (float*)d_out;

  // ws layout (bytes): qkvgb 67,108,864 | xnb 16,777,216 | aoutb 16,777,216 |
  //                    wt 655,360 | bias2 2,097,152   => ~98.6 MB total
  char*  ws    = (char*)d_ws;
  short* qkvgb = (short*)ws;
  short* xnb   = (short*)(ws + 67108864);
  short* aoutb = (short*)(ws + 67108864 + 16777216);
  short* wt    = (short*)(ws + 100663296);
  float* bias2 = (float*)(ws + 101318656);

  k_ln_x<<<MROWS / 4, 256, 0, stream>>>(x, ln_g, ln_b, xnb);
  k_prep<<<1280, 256, 0, stream>>>(Wq, Wkv, Wg, Wo, wt);
  k_bias<<<(WW * WW) / 4, 256, 0, stream>>>(edges, emask, lne_g, lne_b, W_edge, bias2);
  k_gemm<1024, 0><<<(MROWS / 128) * 8, 256, 0, stream>>>(xnb, wt, bg, (void*)qkvgb);
  k_attn<<<RR * H, 256, 0, stream>>>(qkvgb, bias2, mask, aoutb);
  k_gemm<256, 1><<<(MROWS / 128) * 2, 256, 0, stream>>>(aoutb, wt + 262144, bo, (void*)out);
}